// Round 6
// baseline (110.498 us; speedup 1.0000x reference)
//
#include <hip/hip_runtime.h>
#include <hip/hip_bf16.h>

using short8 = __attribute__((ext_vector_type(8))) short;
using f32x4  = __attribute__((ext_vector_type(4))) float;

constexpr int BSZ = 8192;
constexpr int DD  = 512;
constexpr int NC  = 100;
constexpr int NTT = 32;                    // 256-row tiles per dim
constexpr int NB2 = NTT * (NTT + 1) / 2;   // 528 upper-triangle blocks
constexpr int KIT = DD / 32;               // 16 K-tiles (BK=32)
constexpr float INV_T = 1.0f / 0.07f;      // analytic row max = 1/T (diagonal)

static __device__ __forceinline__ ushort f2bf(float x) {
    union { float f; unsigned u; } c; c.f = x;
    unsigned r = c.u + 0x7fffu + ((c.u >> 16) & 1u);   // RNE
    return (ushort)(r >> 16);
}

static __device__ __forceinline__ void gload16(const void* g, void* l) {
    __builtin_amdgcn_global_load_lds((const __attribute__((address_space(1))) void*)g,
                                     (__attribute__((address_space(3))) void*)l, 16, 0, 0);
}

// sum over the 16-lane DPP row via rotate-add (VALU pipe, no LDS traffic)
#define DPPADD(v, ctrl) { \
    int _x = __builtin_amdgcn_update_dpp(0, __float_as_int(v), ctrl, 0xf, 0xf, true); \
    v += __int_as_float(_x); }
#define ROWSUM16(v) { DPPADD(v, 0x128) DPPADD(v, 0x124) DPPADD(v, 0x122) DPPADD(v, 0x121) }

// ---------- kernel 1: L2-normalize rows, fp32 -> bf16 ----------
__global__ __launch_bounds__(256) void norm_rows(const float* __restrict__ feat,
                                                 ushort* __restrict__ fnrm) {
    const int row = blockIdx.x * 4 + (threadIdx.x >> 6);
    const int l   = threadIdx.x & 63;
    const float4* src = reinterpret_cast<const float4*>(feat + (size_t)row * DD);
    float4 v0 = src[l * 2 + 0];
    float4 v1 = src[l * 2 + 1];
    float ss = v0.x*v0.x + v0.y*v0.y + v0.z*v0.z + v0.w*v0.w
             + v1.x*v1.x + v1.y*v1.y + v1.z*v1.z + v1.w*v1.w;
    #pragma unroll
    for (int m = 32; m >= 1; m >>= 1) ss += __shfl_xor(ss, m, 64);
    const float rn = rsqrtf(ss);
    float vals[8] = {v0.x, v0.y, v0.z, v0.w, v1.x, v1.y, v1.z, v1.w};
    ushort u[8];
    #pragma unroll
    for (int j = 0; j < 8; ++j) u[j] = f2bf(vals[j] * rn);
    *reinterpret_cast<short8*>(fnrm + (size_t)row * DD + l * 8) =
        *reinterpret_cast<short8*>(u);
}

// ---------- kernel 2: label histogram (16 blocks, int atomics: deterministic) ----
__global__ __launch_bounds__(256) void label_hist(const int* __restrict__ labels,
                                                  int* __restrict__ counts) {
    __shared__ int lc[NC];
    const int t = threadIdx.x;
    if (t < NC) lc[t] = 0;
    __syncthreads();
    const int base = blockIdx.x * 512;
    for (int i = t; i < 512; i += 256) atomicAdd(&lc[labels[base + i]], 1);
    __syncthreads();
    if (t < NC && lc[t] > 0) atomicAdd(&counts[t], lc[t]);
}

// ---------- kernel 3: fused sim-GEMM, 256^2 tiles, upper-tri, 8 waves ----------
// Per wave: 128x64 output (acc[8][4]). 2 LDS bufs x (A 16K + B 16K). Per K-tile:
// stage next tile (4 gloads/thread) -> 12 ds_read_b128 -> 32 MFMA (setprio) ->
// vmcnt(0)+barrier (stage is one full compute-phase old -> latency covered).
__global__ __launch_bounds__(512, 1) void supcon_main(const ushort* __restrict__ fnrm,
                                                      const int* __restrict__ labels,
                                                      float* __restrict__ part_denom,
                                                      float* __restrict__ part_spos) {
    __shared__ __align__(16) ushort smem[32768];        // 64 KB
    __shared__ int lbl_row[256], lbl_col[256];

    // bijective XCD-contiguous swizzle (528 = 8 * 66)
    const int raw = blockIdx.x;
    const int bid = (raw & 7) * 66 + (raw >> 3);
    int rt = 0, rem = bid;
    while (rem >= NTT - rt) { rem -= NTT - rt; ++rt; }
    const int ct = rt + rem;
    const bool diag = (ct == rt);

    const int t  = threadIdx.x;
    const int w  = t >> 6, l = t & 63;
    const int lr = l & 15, grp = l >> 4;
    const int wr = w >> 2, wc = w & 3;    // 2M x 4N wave grid
    const int rowBase = rt * 256, colBase = ct * 256;

    if (t < 256) lbl_row[t] = labels[rowBase + t];
    else         lbl_col[t - 256] = labels[colBase + (t - 256)];

    // staging: thread t fills physical 16B chunks t and t+512 of each [256][4]
    // chunk tile. Swizzle chunk c -> c ^ ((row>>1)&3), applied by pre-swizzling
    // the global source (LDS dest stays linear per gload_lds rules).
    const ushort* gsA[2]; const ushort* gsB[2];
    #pragma unroll
    for (int j = 0; j < 2; ++j) {
        const int p = t + j * 512;
        const int row = p >> 2, c = p & 3;
        const int cc = c ^ ((row >> 1) & 3);
        gsA[j] = fnrm + (size_t)(rowBase + row) * DD + cc * 8;
        gsB[j] = fnrm + (size_t)(colBase + row) * DD + cc * 8;
    }
    char* s = (char*)smem;

    // ds_read byte offsets (loop-invariant; buf adds an immediate)
    int adsA[8], adsB[4];
    #pragma unroll
    for (int fa = 0; fa < 8; ++fa) {
        const int row = wr * 128 + fa * 16 + lr;
        adsA[fa] = row * 64 + ((grp ^ ((row >> 1) & 3)) << 4);
    }
    #pragma unroll
    for (int fb = 0; fb < 4; ++fb) {
        const int row = wc * 64 + fb * 16 + lr;
        adsB[fb] = 16384 + row * 64 + ((grp ^ ((row >> 1) & 3)) << 4);
    }

    f32x4 acc[8][4];
    #pragma unroll
    for (int i = 0; i < 8; ++i)
        #pragma unroll
        for (int j = 0; j < 4; ++j) acc[i][j] = f32x4{0.f, 0.f, 0.f, 0.f};

    #define STAGE(it, b) { \
        gload16(gsA[0] + (it) * 32, s + (b) * 32768 + t * 16);         \
        gload16(gsA[1] + (it) * 32, s + (b) * 32768 + 8192 + t * 16);  \
        gload16(gsB[0] + (it) * 32, s + (b) * 32768 + 16384 + t * 16); \
        gload16(gsB[1] + (it) * 32, s + (b) * 32768 + 24576 + t * 16); }

    STAGE(0, 0)
    asm volatile("s_waitcnt vmcnt(0)" ::: "memory");
    __builtin_amdgcn_s_barrier();

    #pragma unroll
    for (int it = 0; it < KIT; ++it) {
        if (it + 1 < KIT) STAGE(it + 1, (it + 1) & 1)
        const char* base = s + (it & 1) * 32768;
        short8 bF[4], aF[8];
        #pragma unroll
        for (int fb = 0; fb < 4; ++fb)
            bF[fb] = *reinterpret_cast<const short8*>(base + adsB[fb]);
        #pragma unroll
        for (int fa = 0; fa < 8; ++fa)
            aF[fa] = *reinterpret_cast<const short8*>(base + adsA[fa]);
        __builtin_amdgcn_s_setprio(1);
        #pragma unroll
        for (int fa = 0; fa < 8; ++fa)
            #pragma unroll
            for (int fb = 0; fb < 4; ++fb)
                acc[fa][fb] = __builtin_amdgcn_mfma_f32_16x16x32_bf16(
                    aF[fa], bF[fb], acc[fa][fb], 0, 0, 0);
        __builtin_amdgcn_s_setprio(0);
        if (it + 1 < KIT) {
            asm volatile("s_waitcnt vmcnt(0)" ::: "memory");
            __builtin_amdgcn_s_barrier();
        }
    }
    #undef STAGE

    // ---- epilogue ----
    __syncthreads();                      // K-loop LDS traffic done; smem reusable
    float* red  = reinterpret_cast<float*>(smem);        // [256 row][4 wc][2] = 8 KB
    float* cred = reinterpret_cast<float*>(smem) + 2048; // [256 col][2 wr][2] = 4 KB

    float cdv[4] = {0.f, 0.f, 0.f, 0.f}, csv[4] = {0.f, 0.f, 0.f, 0.f};
    #pragma unroll
    for (int fa = 0; fa < 8; ++fa) {
        #pragma unroll
        for (int r = 0; r < 4; ++r) {
            const int row_l = wr * 128 + fa * 16 + grp * 4 + r;
            const int grow  = rowBase + row_l;
            const int lrow  = lbl_row[row_l];
            float dsum = 0.f, ssum = 0.f;
            #pragma unroll
            for (int fb = 0; fb < 4; ++fb) {
                const int col_l = wc * 64 + fb * 16 + lr;
                const float sim = acc[fa][fb][r] * INV_T;
                const float e   = __expf(sim - INV_T);
                const bool  ok  = (colBase + col_l) != grow;   // self (diag only)
                const bool  pos = (lbl_col[col_l] == lrow);
                const float ev  = ok ? e : 0.f;
                const float sv  = (ok && pos) ? sim : 0.f;
                dsum += ev; ssum += sv;
                cdv[fb] += ev; csv[fb] += sv;
            }
            ROWSUM16(dsum)                // reduce over lr on the VALU (DPP)
            ROWSUM16(ssum)
            if (lr == 0) {
                red[(row_l * 4 + wc) * 2 + 0] = dsum;
                red[(row_l * 4 + wc) * 2 + 1] = ssum;
            }
        }
    }
    #pragma unroll
    for (int fb = 0; fb < 4; ++fb) {      // col-side: reduce over grp
        cdv[fb] += __shfl_xor(cdv[fb], 16, 64); cdv[fb] += __shfl_xor(cdv[fb], 32, 64);
        csv[fb] += __shfl_xor(csv[fb], 16, 64); csv[fb] += __shfl_xor(csv[fb], 32, 64);
    }
    if (grp == 0) {
        #pragma unroll
        for (int fb = 0; fb < 4; ++fb) {
            const int col_l = wc * 64 + fb * 16 + lr;
            cred[(col_l * 2 + wr) * 2 + 0] = cdv[fb];
            cred[(col_l * 2 + wr) * 2 + 1] = csv[fb];
        }
    }
    __syncthreads();
    if (t < 256) {                        // row-side: combine 4 wc partials
        float d = 0.f, sv = 0.f;
        #pragma unroll
        for (int k = 0; k < 4; ++k) {
            d  += red[(t * 4 + k) * 2 + 0];
            sv += red[(t * 4 + k) * 2 + 1];
        }
        part_denom[(size_t)ct * BSZ + rowBase + t] = d;
        part_spos [(size_t)ct * BSZ + rowBase + t] = sv;
    } else if (!diag) {                   // col-side: combine 2 wr partials
        const int c = t - 256;
        const float d  = cred[(c * 2) * 2 + 0] + cred[(c * 2 + 1) * 2 + 0];
        const float sv = cred[(c * 2) * 2 + 1] + cred[(c * 2 + 1) * 2 + 1];
        part_denom[(size_t)rt * BSZ + colBase + c] = d;
        part_spos [(size_t)rt * BSZ + colBase + c] = sv;
    }
}

// ---------- kernel 4: per-row finalize ----------
__global__ __launch_bounds__(256) void row_finalize(const float* __restrict__ part_denom,
                                                    const float* __restrict__ part_spos,
                                                    const int* __restrict__ counts,
                                                    const int* __restrict__ labels,
                                                    float* __restrict__ c_row,
                                                    float* __restrict__ v_row) {
    const int row = blockIdx.x * 256 + threadIdx.x;
    float denom = 0.f, spos = 0.f;
    for (int ctile = 0; ctile < NTT; ++ctile) {
        denom += part_denom[(size_t)ctile * BSZ + row];
        spos  += part_spos [(size_t)ctile * BSZ + row];
    }
    const int   npos  = counts[labels[row]] - 1;
    const float npf   = (float)npos;
    const float mean  = (spos - npf * INV_T - npf * logf(denom + 1e-12f)) / (npf + 1e-12f);
    const bool  valid = npos > 0;
    c_row[row] = valid ? mean : 0.f;
    v_row[row] = valid ? 1.f : 0.f;
}

// ---------- kernel 5: final scalar reduce ----------
__global__ __launch_bounds__(1024) void final_reduce(const float* __restrict__ c_row,
                                                     const float* __restrict__ v_row,
                                                     float* __restrict__ out) {
    __shared__ float sdata[16], vdata[16];
    const int t = threadIdx.x;
    float s = 0.f, v = 0.f;
    for (int i = t; i < BSZ; i += 1024) { s += c_row[i]; v += v_row[i]; }
    #pragma unroll
    for (int m = 32; m >= 1; m >>= 1) { s += __shfl_xor(s, m, 64); v += __shfl_xor(v, m, 64); }
    if ((t & 63) == 0) { sdata[t >> 6] = s; vdata[t >> 6] = v; }
    __syncthreads();
    if (t == 0) {
        float st = 0.f, vt = 0.f;
        #pragma unroll
        for (int i = 0; i < 16; ++i) { st += sdata[i]; vt += vdata[i]; }
        out[0] = -st / fmaxf(vt, 1.f);
    }
}

extern "C" void kernel_launch(void* const* d_in, const int* in_sizes, int n_in,
                              void* d_out, int out_size, void* d_ws, size_t ws_size,
                              hipStream_t stream) {
    const float* feat   = (const float*)d_in[0];
    const int*   labels = (const int*)d_in[1];
    float*       out    = (float*)d_out;

    char* ws = (char*)d_ws;
    ushort* fnrm       = (ushort*)ws;  ws += (size_t)BSZ * DD * 2;   // 8 MB bf16 normalized
    float*  part_denom = (float*)ws;   ws += (size_t)NTT * BSZ * 4;  // 1 MB
    float*  part_spos  = (float*)ws;   ws += (size_t)NTT * BSZ * 4;  // 1 MB
    int*    counts     = (int*)ws;     ws += 512;
    float*  c_row      = (float*)ws;   ws += BSZ * 4;
    float*  v_row      = (float*)ws;   ws += BSZ * 4;

    hipMemsetAsync(counts, 0, NC * sizeof(int), stream);
    hipLaunchKernelGGL(norm_rows,    dim3(BSZ / 4), dim3(256),  0, stream, feat, fnrm);
    hipLaunchKernelGGL(label_hist,   dim3(16),      dim3(256),  0, stream, labels, counts);
    hipLaunchKernelGGL(supcon_main,  dim3(NB2),     dim3(512),  0, stream,
                       fnrm, labels, part_denom, part_spos);
    hipLaunchKernelGGL(row_finalize, dim3(BSZ/256), dim3(256),  0, stream,
                       part_denom, part_spos, counts, labels, c_row, v_row);
    hipLaunchKernelGGL(final_reduce, dim3(1),       dim3(1024), 0, stream, c_row, v_row, out);
}